// Round 14
// baseline (241.183 us; speedup 1.0000x reference)
//
#include <hip/hip_runtime.h>
#include <hip/hip_bf16.h>

// TinySelfAttention: x[2,2048,1024] fp32; Wq/Wk/Wv/Wo [1024,1024] fp32 ([out,in]).
// out = softmax_causal((xWq^T)(xWk^T)^T/8) (xWv^T) Wo^T, fp32.
//
// Pipeline: cast x -> bf16, cast 4 W -> bf16 | fused QKV MFMA GEMM (128^2,
// double-buffered K-tiles, stage-next-before-compute, 1 barrier/iter) ->
// qkv[row][3072] | bf16 MFMA flash attn (folded pairs, K/V dbuf LDS) -> y bf16 |
// MFMA GEMM y@Wo^T -> fp32 out.

#define S_LEN  2048
#define BATCH  2
#define DMODEL 1024
#define NHEADS 16
#define HDIM   64
#define QKV_LD 3072

typedef short short8 __attribute__((ext_vector_type(8)));
typedef float f32x4  __attribute__((ext_vector_type(4)));

__device__ __forceinline__ float b2f(unsigned short u) {
    union { unsigned int i; float f; } x; x.i = ((unsigned int)u) << 16; return x.f;
}
__device__ __forceinline__ unsigned short f2b(float f) {
    union { float f; unsigned int i; } x; x.f = f;
    unsigned int r = x.i + 0x7fffu + ((x.i >> 16) & 1u);  // RNE
    return (unsigned short)(r >> 16);
}

// async global->LDS, 16B per lane; LDS dest = wave-uniform base + lane*16 (HW rule)
__device__ __forceinline__ void gload16(const unsigned short* g, unsigned short* l) {
    __builtin_amdgcn_global_load_lds(
        (const __attribute__((address_space(1))) unsigned int*)g,
        (__attribute__((address_space(3))) unsigned int*)l, 16, 0, 0);
}

// XOR-swizzled accessor for 128B-row LDS tiles (attn; G4 bank-conflict fix).
__device__ __forceinline__ unsigned short* swzp(unsigned short* base, int row, int col) {
    int byte = (col << 1) ^ ((((row >> 3) ^ row) & 7) << 4);
    return base + (row << 6) + (byte >> 1);
}

// ---------------- cast fp32 -> bf16, 4 elems/thread ----------------
__global__ void cast_kernel(const float* __restrict__ in, unsigned short* __restrict__ out, int n4) {
    int i = blockIdx.x * blockDim.x + threadIdx.x;
    if (i >= n4) return;
    float4 v = ((const float4*)in)[i];
    unsigned int lo = (unsigned int)f2b(v.x) | ((unsigned int)f2b(v.y) << 16);
    unsigned int hi = (unsigned int)f2b(v.z) | ((unsigned int)f2b(v.w) << 16);
    ((uint2*)out)[i] = make_uint2(lo, hi);
}

// cast 4 weights (1M floats each) into one contiguous bf16 dest (wqkv | wo)
__global__ void cast_w4(const float* __restrict__ w0, const float* __restrict__ w1,
                        const float* __restrict__ w2, const float* __restrict__ w3,
                        unsigned short* __restrict__ out) {
    int i = blockIdx.x * blockDim.x + threadIdx.x;     // over 4M/4 = 1M float4
    if (i >= (1 << 20)) return;
    int seg = i >> 18;                                 // 2^18 float4 per weight
    const float* src = seg == 0 ? w0 : seg == 1 ? w1 : seg == 2 ? w2 : w3;
    float4 v = ((const float4*)src)[i & 0x3FFFF];
    unsigned int lo = (unsigned int)f2b(v.x) | ((unsigned int)f2b(v.y) << 16);
    unsigned int hi = (unsigned int)f2b(v.z) | ((unsigned int)f2b(v.w) << 16);
    ((uint2*)out)[i] = make_uint2(lo, hi);
}

// ---------------- bf16 MFMA GEMM: C[M,N] = A[M,K] @ W[N,K]^T ----------------
// 128x128 tile, BK=64, 256 threads (4 waves, 2x2 of 64x64), global_load_lds(16B).
// T3-minimum 2-phase: K-tile double-buffer, STAGE(next) issued BEFORE
// COMPUTE(cur), ONE __syncthreads per iter (its vmcnt(0) drain lands after the
// compute phase has covered the load latency). LDS 64 KB -> 2 blocks/CU.
// OUT_BF16==1 (QKV gemm): cols < DMODEL (the Q block) are pre-scaled by 1/8.
template<int OUT_BF16>
__global__ __launch_bounds__(256) void gemm128(const unsigned short* __restrict__ A,
                                               const unsigned short* __restrict__ W,
                                               unsigned short* __restrict__ Cb,
                                               float* __restrict__ Cf,
                                               int N, int K) {
    __shared__ unsigned short As[2][128 * 64];
    __shared__ unsigned short Bs[2][128 * 64];
    const int tid  = threadIdx.x;
    const int lane = tid & 63;
    const int wave = tid >> 6;
    const int bm = blockIdx.y * 128;
    const int bn = blockIdx.x * 128;
    const int wr = (wave >> 1) * 64;
    const int wc = (wave & 1) * 64;
    const int l15 = lane & 15;
    const int l4  = lane >> 4;

    // staging: wave w covers tile rows [w*32, w*32+32), 4 instrs x 8 rows each;
    // lane l -> row l>>3, col (l&7)*8 shorts (matches linear LDS base+lane*16B)
    const int srow = wave * 32 + (lane >> 3);
    const int scol = (lane & 7) * 8;
    const unsigned short* Ag = A + (size_t)(bm + srow) * K + scol;
    const unsigned short* Wg = W + (size_t)(bn + srow) * K + scol;

    f32x4 acc[4][4];
#pragma unroll
    for (int i = 0; i < 4; ++i)
#pragma unroll
        for (int j = 0; j < 4; ++j) acc[i][j] = (f32x4){0.f, 0.f, 0.f, 0.f};

    auto STAGE = [&](int buf, int k0) {
        unsigned short* Al = &As[buf][wave * 32 * 64];
        unsigned short* Bl = &Bs[buf][wave * 32 * 64];
#pragma unroll
        for (int i = 0; i < 4; ++i) {
            gload16(Ag + k0 + (size_t)(i * 8) * K, Al + i * 8 * 64);
            gload16(Wg + k0 + (size_t)(i * 8) * K, Bl + i * 8 * 64);
        }
    };
    auto COMPUTE = [&](int buf) {
#pragma unroll
        for (int kk = 0; kk < 2; ++kk) {
            short8 af[4], bf[4];
#pragma unroll
            for (int mi = 0; mi < 4; ++mi)
                af[mi] = *(const short8*)&As[buf][(wr + mi * 16 + l15) * 64 + kk * 32 + l4 * 8];
#pragma unroll
            for (int ni = 0; ni < 4; ++ni)
                bf[ni] = *(const short8*)&Bs[buf][(wc + ni * 16 + l15) * 64 + kk * 32 + l4 * 8];
#pragma unroll
            for (int mi = 0; mi < 4; ++mi)
#pragma unroll
                for (int ni = 0; ni < 4; ++ni)
                    acc[mi][ni] = __builtin_amdgcn_mfma_f32_16x16x32_bf16(af[mi], bf[ni], acc[mi][ni], 0, 0, 0);
        }
    };

    // prologue: tile 0 -> buf 0
    STAGE(0, 0);
    __syncthreads();            // vmcnt(0) drain: buf 0 ready
    int cur = 0;
    for (int k0 = 64; k0 < K; k0 += 64) {
        STAGE(cur ^ 1, k0);     // issue next-tile loads FIRST (overlap compute)
        COMPUTE(cur);           // ds_read + MFMA cover the load latency
        __syncthreads();        // drains staged loads + all reads of buf cur
        cur ^= 1;
    }
    COMPUTE(cur);               // last tile, no prefetch

    // epilogue: C/D layout col=lane&15, row=(lane>>4)*4+i (HW-verified)
#pragma unroll
    for (int mi = 0; mi < 4; ++mi)
#pragma unroll
        for (int ni = 0; ni < 4; ++ni)
#pragma unroll
            for (int i = 0; i < 4; ++i) {
                int row = bm + wr + mi * 16 + l4 * 4 + i;
                int col = bn + wc + ni * 16 + l15;
                float v = acc[mi][ni][i];
                if constexpr (OUT_BF16) {
                    if (col < DMODEL) v *= 0.125f;   // pre-scale Q (exact pow2)
                    Cb[(size_t)row * N + col] = f2b(v);
                } else {
                    Cf[(size_t)row * N + col] = v;
                }
            }
}

// ---------------- bf16 MFMA flash attention (causal) ----------------
// Block = (b, h, folded q-tile pair {f, 31-f}): 512 blocks, uniform 33 kv-tiles.
// K/V double-buffered in LDS, one barrier per kv-tile, reg prefetch.
// 4 waves x 16 q-rows. Q is pre-scaled by 1/8 in the QKV GEMM.
__global__ __launch_bounds__(256) void attn_mfma(const unsigned short* __restrict__ Qp,
                                                 const unsigned short* __restrict__ Kp,
                                                 const unsigned short* __restrict__ Vp,
                                                 unsigned short* __restrict__ Yp) {
    __shared__ unsigned short Ks[2][64 * 64];  // K[key][d], double-buffered
    __shared__ unsigned short Vt[2][64 * 64];  // V^T[d][key], double-buffered
    __shared__ unsigned short Pl[4 * 16 * 64]; // per-wave P[q][key]
    const int tid  = threadIdx.x;
    const int lane = tid & 63;
    const int wq   = tid >> 6;
    const int l15  = lane & 15;
    const int l4   = lane >> 4;
    const int r    = tid >> 2;
    const int c4   = tid & 3;
    const int h = blockIdx.y, b = blockIdx.z;
    unsigned short* Pw = Pl + wq * (16 * 64);

#pragma unroll 1
    for (int qp = 0; qp < 2; ++qp) {
        const int qt = qp ? (31 - (int)blockIdx.x) : (int)blockIdx.x;
        short8 qf0, qf1;
        {
            const unsigned short* qb = Qp + ((size_t)(b * S_LEN + qt * 64 + wq * 16 + l15)) * QKV_LD
                                          + h * HDIM + l4 * 8;
            qf0 = *(const short8*)qb;
            qf1 = *(const short8*)(qb + 32);
        }
        f32x4 oacc[4];
        float mrow[4], lrow[4];
#pragma unroll
        for (int t = 0; t < 4; ++t) oacc[t] = (f32x4){0.f, 0.f, 0.f, 0.f};
#pragma unroll
        for (int i = 0; i < 4; ++i) { mrow[i] = -1e30f; lrow[i] = 0.f; }

        // prologue: load kv-tile 0 into registers
        uint4 rk0, rk1, rv0, rv1;
        {
            const size_t gb = ((size_t)(b * S_LEN + r)) * QKV_LD + h * HDIM + c4 * 16;
            rk0 = *(const uint4*)(Kp + gb);
            rk1 = *(const uint4*)(Kp + gb + 8);
            rv0 = *(const uint4*)(Vp + gb);
            rv1 = *(const uint4*)(Vp + gb + 8);
        }

#pragma unroll 1
        for (int kt = 0; kt <= qt; ++kt) {
            const int cur = kt & 1;
            unsigned short* Kc = (unsigned short*)Ks[cur];
            unsigned short* Vc = (unsigned short*)Vt[cur];
            *(uint4*)swzp(Kc, r, c4 * 16)     = rk0;
            *(uint4*)swzp(Kc, r, c4 * 16 + 8) = rk1;
            {
                const unsigned short* vs = (const unsigned short*)&rv0;
#pragma unroll
                for (int j = 0; j < 8; ++j) *swzp(Vc, c4 * 16 + j, r) = vs[j];
                vs = (const unsigned short*)&rv1;
#pragma unroll
                for (int j = 0; j < 8; ++j) *swzp(Vc, c4 * 16 + 8 + j, r) = vs[j];
            }
            if (kt < qt) {
                const size_t gb = ((size_t)(b * S_LEN + (kt + 1) * 64 + r)) * QKV_LD
                                  + h * HDIM + c4 * 16;
                rk0 = *(const uint4*)(Kp + gb);
                rk1 = *(const uint4*)(Kp + gb + 8);
                rv0 = *(const uint4*)(Vp + gb);
                rv1 = *(const uint4*)(Vp + gb + 8);
            }
            __syncthreads();   // buf `cur` visible to all waves

            f32x4 sc[4];
#pragma unroll
            for (int t = 0; t < 4; ++t) sc[t] = (f32x4){0.f, 0.f, 0.f, 0.f};
#pragma unroll
            for (int t = 0; t < 4; ++t) {
                short8 kf = *(const short8*)swzp(Kc, t * 16 + l15, l4 * 8);
                sc[t] = __builtin_amdgcn_mfma_f32_16x16x32_bf16(qf0, kf, sc[t], 0, 0, 0);
            }
#pragma unroll
            for (int t = 0; t < 4; ++t) {
                short8 kf = *(const short8*)swzp(Kc, t * 16 + l15, 32 + l4 * 8);
                sc[t] = __builtin_amdgcn_mfma_f32_16x16x32_bf16(qf1, kf, sc[t], 0, 0, 0);
            }
            const bool diag = (kt == qt);
#pragma unroll
            for (int t = 0; t < 4; ++t)
#pragma unroll
                for (int i = 0; i < 4; ++i) {
                    float s = sc[t][i];   // Q pre-scaled by 1/8 in GEMM
                    if (diag && (t * 16 + l15 > wq * 16 + l4 * 4 + i)) s = -1e30f;
                    sc[t][i] = s;
                }
#pragma unroll
            for (int i = 0; i < 4; ++i) {
                float mx = fmaxf(fmaxf(sc[0][i], sc[1][i]), fmaxf(sc[2][i], sc[3][i]));
                mx = fmaxf(mx, __shfl_xor(mx, 1));
                mx = fmaxf(mx, __shfl_xor(mx, 2));
                mx = fmaxf(mx, __shfl_xor(mx, 4));
                mx = fmaxf(mx, __shfl_xor(mx, 8));
                const float mn = fmaxf(mrow[i], mx);
                const float al = __expf(mrow[i] - mn);
                mrow[i] = mn;
                float ls = 0.f;
#pragma unroll
                for (int t = 0; t < 4; ++t) {
                    float p = __expf(sc[t][i] - mn);
                    sc[t][i] = p;
                    ls += p;
                }
                ls += __shfl_xor(ls, 1);
                ls += __shfl_xor(ls, 2);
                ls += __shfl_xor(ls, 4);
                ls += __shfl_xor(ls, 8);
                lrow[i] = lrow[i] * al + ls;
#pragma unroll
                for (int t = 0; t < 4; ++t) oacc[t][i] *= al;
            }
#pragma unroll
            for (int t = 0; t < 4; ++t)
#pragma unroll
                for (int i = 0; i < 4; ++i)
                    *swzp(Pw, l4 * 4 + i, t * 16 + l15) = f2b(sc[t][i]);

            short8 pf0 = *(const short8*)swzp(Pw, l15, l4 * 8);
            short8 pf1 = *(const short8*)swzp(Pw, l15, 32 + l4 * 8);
#pragma unroll
            for (int td = 0; td < 4; ++td) {
                short8 vf = *(const short8*)swzp(Vc, td * 16 + l15, l4 * 8);
                oacc[td] = __builtin_amdgcn_mfma_f32_16x16x32_bf16(pf0, vf, oacc[td], 0, 0, 0);
            }
#pragma unroll
            for (int td = 0; td < 4; ++td) {
                short8 vf = *(const short8*)swzp(Vc, td * 16 + l15, 32 + l4 * 8);
                oacc[td] = __builtin_amdgcn_mfma_f32_16x16x32_bf16(pf1, vf, oacc[td], 0, 0, 0);
            }
        }
        __syncthreads();   // qp=1 reuses buf 0: wait for all waves' last compute

        float linv[4];
#pragma unroll
        for (int i = 0; i < 4; ++i) linv[i] = 1.0f / lrow[i];
        unsigned short* yb = Yp + ((size_t)(b * S_LEN + qt * 64 + wq * 16 + l4 * 4)) * DMODEL
                                + h * HDIM + l15;
#pragma unroll
        for (int i = 0; i < 4; ++i)
#pragma unroll
            for (int td = 0; td < 4; ++td)
                yb[(size_t)i * DMODEL + td * 16] = f2b(oacc[td][i] * linv[i]);
    }
}

extern "C" void kernel_launch(void* const* d_in, const int* in_sizes, int n_in,
                              void* d_out, int out_size, void* d_ws, size_t ws_size,
                              hipStream_t stream) {
    (void)in_sizes; (void)n_in; (void)out_size; (void)ws_size;
    const float* x  = (const float*)d_in[0];
    const float* Wq = (const float*)d_in[1];
    const float* Wk = (const float*)d_in[2];
    const float* Wv = (const float*)d_in[3];
    const float* Wo = (const float*)d_in[4];
    float* out = (float*)d_out;

    const size_t nx = (size_t)BATCH * S_LEN * DMODEL;   // 4,194,304
    const size_t nw = (size_t)DMODEL * DMODEL;          // 1,048,576
    char* ws = (char*)d_ws;
    unsigned short* xb    = (unsigned short*)ws; ws += nx * 2;          // 8 MB
    unsigned short* wqkvb = (unsigned short*)ws; ws += nw * 3 * 2;      // 6 MB (Wq|Wk|Wv rows)
    unsigned short* wob   = (unsigned short*)ws; ws += nw * 2;          // 2 MB (contiguous after wqkvb)
    unsigned short* qkv   = (unsigned short*)ws; ws += nx * 3 * 2;      // 24 MB [row][3072]
    unsigned short* yb    = (unsigned short*)ws; ws += nx * 2;          // 8 MB  -> 48 MB total

    cast_kernel<<<(int)(nx / 4 + 255) / 256, 256, 0, stream>>>(x, xb, (int)(nx / 4));
    cast_w4<<<(1 << 20) / 256, 256, 0, stream>>>(Wq, Wk, Wv, Wo, wqkvb);  // dest = wqkv|wo

    dim3 gq(QKV_LD / 128, (BATCH * S_LEN) / 128);   // 24 x 32
    gemm128<1><<<gq, 256, 0, stream>>>(xb, wqkvb, qkv, nullptr, QKV_LD, DMODEL);

    dim3 ga(S_LEN / 128, NHEADS, BATCH);            // 16 folded q-tile pairs = 512 blocks
    attn_mfma<<<ga, 256, 0, stream>>>(qkv, qkv + DMODEL, qkv + 2 * DMODEL, yb);

    dim3 go(DMODEL / 128, (BATCH * S_LEN) / 128);   // 8 x 32
    gemm128<0><<<go, 256, 0, stream>>>(yb, wob, nullptr, out, DMODEL, DMODEL);
}

// Round 15
// 224.341 us; speedup vs baseline: 1.0751x; 1.0751x over previous
//
#include <hip/hip_runtime.h>
#include <hip/hip_bf16.h>

// TinySelfAttention: x[2,2048,1024] fp32; Wq/Wk/Wv/Wo [1024,1024] fp32 ([out,in]).
// out = softmax_causal((xWq^T)(xWk^T)^T/8) (xWv^T) Wo^T, fp32.
//
// Pipeline: cast x+4W -> bf16 (one kernel) | fused QKV MFMA GEMM (128^2,
// single-buffer global_load_lds, Q pre-scaled 1/8) -> qkv[row][3072] |
// bf16 MFMA flash attn (folded pairs, KVBLK=128) -> y bf16 |
// MFMA GEMM y@Wo^T -> fp32 out.

#define S_LEN  2048
#define BATCH  2
#define DMODEL 1024
#define NHEADS 16
#define HDIM   64
#define QKV_LD 3072

typedef short short8 __attribute__((ext_vector_type(8)));
typedef float f32x4  __attribute__((ext_vector_type(4)));

__device__ __forceinline__ float b2f(unsigned short u) {
    union { unsigned int i; float f; } x; x.i = ((unsigned int)u) << 16; return x.f;
}
__device__ __forceinline__ unsigned short f2b(float f) {
    union { float f; unsigned int i; } x; x.f = f;
    unsigned int r = x.i + 0x7fffu + ((x.i >> 16) & 1u);  // RNE
    return (unsigned short)(r >> 16);
}

// async global->LDS, 16B per lane; LDS dest = wave-uniform base + lane*16 (HW rule)
__device__ __forceinline__ void gload16(const unsigned short* g, unsigned short* l) {
    __builtin_amdgcn_global_load_lds(
        (const __attribute__((address_space(1))) unsigned int*)g,
        (__attribute__((address_space(3))) unsigned int*)l, 16, 0, 0);
}

// XOR-swizzled accessors (G4 bank-conflict fix), bijective per row, 16B-aligned.
__device__ __forceinline__ unsigned short* swz64(unsigned short* base, int row, int col) {
    int byte = (col << 1) ^ ((((row >> 3) ^ row) & 7) << 4);   // 64-short rows
    return base + (row << 6) + (byte >> 1);
}
__device__ __forceinline__ unsigned short* swz128(unsigned short* base, int row, int col) {
    int byte = (col << 1) ^ ((((row >> 3) ^ row) & 7) << 4);   // 128-short rows
    return base + (row << 7) + (byte >> 1);
}

// ---------------- cast x + 4 weights -> bf16, one kernel ----------------
__global__ void cast_all(const float* __restrict__ x,
                         const float* __restrict__ w0, const float* __restrict__ w1,
                         const float* __restrict__ w2, const float* __restrict__ w3,
                         unsigned short* __restrict__ xb, unsigned short* __restrict__ wout) {
    int i = blockIdx.x * blockDim.x + threadIdx.x;     // over 2^21 float4
    float4 v;
    unsigned short* dst;
    if (i < (1 << 20)) {                               // x: 2^20 float4
        v = ((const float4*)x)[i];
        dst = xb + (size_t)i * 4;
    } else {
        int j = i - (1 << 20);                         // weights: 4 x 2^18 float4
        int seg = j >> 18;
        const float* src = seg == 0 ? w0 : seg == 1 ? w1 : seg == 2 ? w2 : w3;
        v = ((const float4*)src)[j & 0x3FFFF];
        dst = wout + (size_t)j * 4;
    }
    unsigned int lo = (unsigned int)f2b(v.x) | ((unsigned int)f2b(v.y) << 16);
    unsigned int hi = (unsigned int)f2b(v.z) | ((unsigned int)f2b(v.w) << 16);
    *(uint2*)dst = make_uint2(lo, hi);
}

// ---------------- bf16 MFMA GEMM: C[M,N] = A[M,K] @ W[N,K]^T ----------------
// Round-11 proven structure: 128x128 tile, BK=64, 4 waves, single-buffer
// linear LDS + global_load_lds(16B), 2-barrier loop (32 KB LDS, ~4 blocks/CU).
// OUT_BF16==1 (QKV gemm): cols < DMODEL (the Q block) are pre-scaled by 1/8.
template<int OUT_BF16>
__global__ __launch_bounds__(256) void gemm128(const unsigned short* __restrict__ A,
                                               const unsigned short* __restrict__ W,
                                               unsigned short* __restrict__ Cb,
                                               float* __restrict__ Cf,
                                               int N, int K) {
    __shared__ unsigned short As[128 * 64];
    __shared__ unsigned short Bs[128 * 64];
    const int tid  = threadIdx.x;
    const int lane = tid & 63;
    const int wave = tid >> 6;
    const int bm = blockIdx.y * 128;
    const int bn = blockIdx.x * 128;
    const int wr = (wave >> 1) * 64;
    const int wc = (wave & 1) * 64;
    const int l15 = lane & 15;
    const int l4  = lane >> 4;

    const int srow = wave * 32 + (lane >> 3);
    const int scol = (lane & 7) * 8;
    const unsigned short* Ag = A + (size_t)(bm + srow) * K + scol;
    const unsigned short* Wg = W + (size_t)(bn + srow) * K + scol;
    unsigned short* Al = As + wave * 32 * 64;
    unsigned short* Bl = Bs + wave * 32 * 64;

    f32x4 acc[4][4];
#pragma unroll
    for (int i = 0; i < 4; ++i)
#pragma unroll
        for (int j = 0; j < 4; ++j) acc[i][j] = (f32x4){0.f, 0.f, 0.f, 0.f};

    for (int k0 = 0; k0 < K; k0 += 64) {
        __syncthreads();   // previous iteration's ds_reads done
#pragma unroll
        for (int i = 0; i < 4; ++i) {
            gload16(Ag + k0 + (size_t)(i * 8) * K, Al + i * 8 * 64);
            gload16(Wg + k0 + (size_t)(i * 8) * K, Bl + i * 8 * 64);
        }
        __syncthreads();   // drains vmcnt(0): staged data visible
#pragma unroll
        for (int kk = 0; kk < 2; ++kk) {
            short8 af[4], bf[4];
#pragma unroll
            for (int mi = 0; mi < 4; ++mi)
                af[mi] = *(const short8*)&As[(wr + mi * 16 + l15) * 64 + kk * 32 + l4 * 8];
#pragma unroll
            for (int ni = 0; ni < 4; ++ni)
                bf[ni] = *(const short8*)&Bs[(wc + ni * 16 + l15) * 64 + kk * 32 + l4 * 8];
#pragma unroll
            for (int mi = 0; mi < 4; ++mi)
#pragma unroll
                for (int ni = 0; ni < 4; ++ni)
                    acc[mi][ni] = __builtin_amdgcn_mfma_f32_16x16x32_bf16(af[mi], bf[ni], acc[mi][ni], 0, 0, 0);
        }
    }
    // epilogue: C/D layout col=lane&15, row=(lane>>4)*4+i (HW-verified)
#pragma unroll
    for (int mi = 0; mi < 4; ++mi)
#pragma unroll
        for (int ni = 0; ni < 4; ++ni)
#pragma unroll
            for (int i = 0; i < 4; ++i) {
                int row = bm + wr + mi * 16 + l4 * 4 + i;
                int col = bn + wc + ni * 16 + l15;
                float v = acc[mi][ni][i];
                if constexpr (OUT_BF16) {
                    if (col < DMODEL) v *= 0.125f;   // pre-scale Q (exact pow2)
                    Cb[(size_t)row * N + col] = f2b(v);
                } else {
                    Cf[(size_t)row * N + col] = v;
                }
            }
}

// ---------------- bf16 MFMA flash attention (causal), KVBLK=128 ----------------
// Block = (b, h, folded q-tile pair {f, 31-f}): 512 blocks, EXACTLY 17
// 128-key iters per block for every f (uniform). Halves barriers, softmax
// shfl chains, rescale passes and loop overhead per key vs KVBLK=64.
// 4 waves x 16 q-rows; QK^T and PV on mfma_f32_16x16x32_bf16.
// Q pre-scaled by 1/8 in the QKV GEMM. LDS 48 KB.
__global__ __launch_bounds__(256) void attn_mfma(const unsigned short* __restrict__ Qp,
                                                 const unsigned short* __restrict__ Kp,
                                                 const unsigned short* __restrict__ Vp,
                                                 unsigned short* __restrict__ Yp) {
    __shared__ unsigned short Ks[128 * 64];     // K[key][d], 64-short rows
    __shared__ unsigned short Vt[64 * 128];     // V^T[d][key], 128-short rows
    __shared__ unsigned short Pl[4 * 16 * 128]; // per-wave P[q][key], 128-short rows
    const int tid  = threadIdx.x;
    const int lane = tid & 63;
    const int wq   = tid >> 6;
    const int l15  = lane & 15;
    const int l4   = lane >> 4;
    const int rk   = tid >> 1;        // staging key row 0..127
    const int ck   = (tid & 1) * 32;  // staging 32-short d-chunk
    const int h = blockIdx.y, b = blockIdx.z;
    unsigned short* Pw = Pl + wq * (16 * 128);

#pragma unroll 1
    for (int qp = 0; qp < 2; ++qp) {
        const int qt = qp ? (31 - (int)blockIdx.x) : (int)blockIdx.x;
        short8 qf0, qf1;
        {
            const unsigned short* qb = Qp + ((size_t)(b * S_LEN + qt * 64 + wq * 16 + l15)) * QKV_LD
                                          + h * HDIM + l4 * 8;
            qf0 = *(const short8*)qb;
            qf1 = *(const short8*)(qb + 32);
        }
        f32x4 oacc[4];
        float mrow[4], lrow[4];
#pragma unroll
        for (int t = 0; t < 4; ++t) oacc[t] = (f32x4){0.f, 0.f, 0.f, 0.f};
#pragma unroll
        for (int i = 0; i < 4; ++i) { mrow[i] = -1e30f; lrow[i] = 0.f; }

        const int nk = qt / 2 + 1;    // 128-key blocks (last may be half-masked)
#pragma unroll 1
        for (int kb = 0; kb < nk; ++kb) {
            __syncthreads();   // previous iteration's (and previous qp's) reads done
            {   // stage K tile (row-major) + transposed V tile
                const size_t gb = ((size_t)(b * S_LEN + kb * 128 + rk)) * QKV_LD + h * HDIM + ck;
                uint4 k0 = *(const uint4*)(Kp + gb);
                uint4 k1 = *(const uint4*)(Kp + gb + 8);
                uint4 k2 = *(const uint4*)(Kp + gb + 16);
                uint4 k3 = *(const uint4*)(Kp + gb + 24);
                uint4 v0 = *(const uint4*)(Vp + gb);
                uint4 v1 = *(const uint4*)(Vp + gb + 8);
                uint4 v2 = *(const uint4*)(Vp + gb + 16);
                uint4 v3 = *(const uint4*)(Vp + gb + 24);
                *(uint4*)swz64(Ks, rk, ck)      = k0;
                *(uint4*)swz64(Ks, rk, ck + 8)  = k1;
                *(uint4*)swz64(Ks, rk, ck + 16) = k2;
                *(uint4*)swz64(Ks, rk, ck + 24) = k3;
                const unsigned short* vs;
                vs = (const unsigned short*)&v0;
#pragma unroll
                for (int j = 0; j < 8; ++j) *swz128(Vt, ck + j, rk) = vs[j];
                vs = (const unsigned short*)&v1;
#pragma unroll
                for (int j = 0; j < 8; ++j) *swz128(Vt, ck + 8 + j, rk) = vs[j];
                vs = (const unsigned short*)&v2;
#pragma unroll
                for (int j = 0; j < 8; ++j) *swz128(Vt, ck + 16 + j, rk) = vs[j];
                vs = (const unsigned short*)&v3;
#pragma unroll
                for (int j = 0; j < 8; ++j) *swz128(Vt, ck + 24 + j, rk) = vs[j];
            }
            __syncthreads();

            // QK^T: 8 key-subtiles of 16
            f32x4 sc[8];
#pragma unroll
            for (int t = 0; t < 8; ++t) sc[t] = (f32x4){0.f, 0.f, 0.f, 0.f};
#pragma unroll
            for (int t = 0; t < 8; ++t) {
                short8 kf = *(const short8*)swz64(Ks, t * 16 + l15, l4 * 8);
                sc[t] = __builtin_amdgcn_mfma_f32_16x16x32_bf16(qf0, kf, sc[t], 0, 0, 0);
            }
#pragma unroll
            for (int t = 0; t < 8; ++t) {
                short8 kf = *(const short8*)swz64(Ks, t * 16 + l15, 32 + l4 * 8);
                sc[t] = __builtin_amdgcn_mfma_f32_16x16x32_bf16(qf1, kf, sc[t], 0, 0, 0);
            }
            // causal mask only on the last (diagonal) block
            if (kb == nk - 1) {
#pragma unroll
                for (int t = 0; t < 8; ++t)
#pragma unroll
                    for (int i = 0; i < 4; ++i) {
                        const int key = kb * 128 + t * 16 + l15;
                        const int qg  = qt * 64 + wq * 16 + l4 * 4 + i;
                        if (key > qg) sc[t][i] = -1e30f;
                    }
            }
            // online softmax per owned row (16-lane row groups share l4)
#pragma unroll
            for (int i = 0; i < 4; ++i) {
                float mx = sc[0][i];
#pragma unroll
                for (int t = 1; t < 8; ++t) mx = fmaxf(mx, sc[t][i]);
                mx = fmaxf(mx, __shfl_xor(mx, 1));
                mx = fmaxf(mx, __shfl_xor(mx, 2));
                mx = fmaxf(mx, __shfl_xor(mx, 4));
                mx = fmaxf(mx, __shfl_xor(mx, 8));
                const float mn = fmaxf(mrow[i], mx);
                const float al = __expf(mrow[i] - mn);   // first block: 0
                mrow[i] = mn;
                float ls = 0.f;
#pragma unroll
                for (int t = 0; t < 8; ++t) {
                    float p = __expf(sc[t][i] - mn);
                    sc[t][i] = p;
                    ls += p;
                }
                ls += __shfl_xor(ls, 1);
                ls += __shfl_xor(ls, 2);
                ls += __shfl_xor(ls, 4);
                ls += __shfl_xor(ls, 8);
                lrow[i] = lrow[i] * al + ls;
#pragma unroll
                for (int td = 0; td < 4; ++td) oacc[td][i] *= al;
            }
            // P (C-layout) -> wave-private LDS (A-layout); wave-local, no barrier
#pragma unroll
            for (int t = 0; t < 8; ++t)
#pragma unroll
                for (int i = 0; i < 4; ++i)
                    *swz128(Pw, l4 * 4 + i, t * 16 + l15) = f2b(sc[t][i]);

            // PV: O[q][d] += P[q][k] V[k][d] over 4 key-slot groups of 32
#pragma unroll
            for (int ks = 0; ks < 4; ++ks) {
                short8 pf = *(const short8*)swz128(Pw, l15, ks * 32 + l4 * 8);
#pragma unroll
                for (int td = 0; td < 4; ++td) {
                    short8 vf = *(const short8*)swz128(Vt, td * 16 + l15, ks * 32 + l4 * 8);
                    oacc[td] = __builtin_amdgcn_mfma_f32_16x16x32_bf16(pf, vf, oacc[td], 0, 0, 0);
                }
            }
        }
        // epilogue: normalize + store (row=wq*16+l4*4+i, col=td*16+l15)
        float linv[4];
#pragma unroll
        for (int i = 0; i < 4; ++i) linv[i] = 1.0f / lrow[i];
        unsigned short* yb = Yp + ((size_t)(b * S_LEN + qt * 64 + wq * 16 + l4 * 4)) * DMODEL
                                + h * HDIM + l15;
#pragma unroll
        for (int i = 0; i < 4; ++i)
#pragma unroll
            for (int td = 0; td < 4; ++td)
                yb[(size_t)i * DMODEL + td * 16] = f2b(oacc[td][i] * linv[i]);
    }
}

extern "C" void kernel_launch(void* const* d_in, const int* in_sizes, int n_in,
                              void* d_out, int out_size, void* d_ws, size_t ws_size,
                              hipStream_t stream) {
    (void)in_sizes; (void)n_in; (void)out_size; (void)ws_size;
    const float* x  = (const float*)d_in[0];
    const float* Wq = (const float*)d_in[1];
    const float* Wk = (const float*)d_in[2];
    const float* Wv = (const float*)d_in[3];
    const float* Wo = (const float*)d_in[4];
    float* out = (float*)d_out;

    const size_t nx = (size_t)BATCH * S_LEN * DMODEL;   // 4,194,304
    const size_t nw = (size_t)DMODEL * DMODEL;          // 1,048,576
    char* ws = (char*)d_ws;
    unsigned short* xb    = (unsigned short*)ws; ws += nx * 2;          // 8 MB
    unsigned short* wqkvb = (unsigned short*)ws; ws += nw * 3 * 2;      // 6 MB (Wq|Wk|Wv rows)
    unsigned short* wob   = (unsigned short*)ws; ws += nw * 2;          // 2 MB (contiguous after wqkvb)
    unsigned short* qkv   = (unsigned short*)ws; ws += nx * 3 * 2;      // 24 MB [row][3072]
    unsigned short* yb    = (unsigned short*)ws; ws += nx * 2;          // 8 MB  -> 48 MB total

    cast_all<<<(1 << 21) / 256, 256, 0, stream>>>(x, Wq, Wk, Wv, Wo, xb, wqkvb);

    dim3 gq(QKV_LD / 128, (BATCH * S_LEN) / 128);   // 24 x 32
    gemm128<1><<<gq, 256, 0, stream>>>(xb, wqkvb, qkv, nullptr, QKV_LD, DMODEL);

    dim3 ga(S_LEN / 128, NHEADS, BATCH);            // 16 folded q-tile pairs = 512 blocks
    attn_mfma<<<ga, 256, 0, stream>>>(qkv, qkv + DMODEL, qkv + 2 * DMODEL, yb);

    dim3 go(DMODEL / 128, (BATCH * S_LEN) / 128);   // 8 x 32
    gemm128<0><<<go, 256, 0, stream>>>(yb, wob, nullptr, out, DMODEL, DMODEL);
}